// Round 16
// baseline (273.378 us; speedup 1.0000x reference)
//
#include <hip/hip_runtime.h>
#include <hip/hip_bf16.h>
#include <stdint.h>

typedef __hip_bfloat16 bf16;
typedef __attribute__((ext_vector_type(8))) short short8;
typedef __attribute__((ext_vector_type(4))) short short4v;
typedef __attribute__((ext_vector_type(4))) float float4v;

static constexpr int nB = 2, nS = 2048, nD = 1024, nH = 16, nHD = 64;
static constexpr int nBS = nB * nS;   // 4096

#define AS_GLOBAL __attribute__((address_space(1)))
#define AS_LDS    __attribute__((address_space(3)))

union Frag16B { short8 v; uint4 u4; uint2 u2[2]; };

__device__ __forceinline__ void gload_lds16(const void* g, void* l) {
  __builtin_amdgcn_global_load_lds((AS_GLOBAL uint32_t*)(g), (AS_LDS uint32_t*)(l), 16, 0, 0);
}

__device__ __forceinline__ float fast_exp2(float x) {
#if __has_builtin(__builtin_amdgcn_exp2f)
  return __builtin_amdgcn_exp2f(x);
#else
  float r; asm volatile("v_exp_f32 %0, %1" : "=v"(r) : "v"(x)); return r;
#endif
}

// drain LDS ops but NOT vmem: prefetch global loads stay in flight across the barrier
__device__ __forceinline__ void lds_barrier() {
  asm volatile("s_waitcnt lgkmcnt(0)\ns_barrier" ::: "memory");
}

__device__ __forceinline__ void lgkm_wait() {
  asm volatile("s_waitcnt lgkmcnt(0)" ::: "memory");
}

static constexpr float SC = 0.18033688011112042f;  // 0.125 * log2(e), folded into Q at projection

// ---------------------------------------------------------------- prep: cast QKV->bf16, W->W^T bf16, rope tables
__global__ __launch_bounds__(256) void prep_kernel(
    const float* __restrict__ Qin, const float* __restrict__ Kin, const float* __restrict__ Vin,
    const float* __restrict__ Wq, const float* __restrict__ Wk,
    const float* __restrict__ Wv, const float* __restrict__ Wo,
    bf16* __restrict__ Qbf, bf16* __restrict__ Kbf, bf16* __restrict__ Vbf,
    bf16* __restrict__ WqT, bf16* __restrict__ WkT, bf16* __restrict__ WvT, bf16* __restrict__ WoT,
    bf16* __restrict__ cos_t, bf16* __restrict__ sin_t) {
  __shared__ float tile[64][65];
  int bx = blockIdx.x, t = threadIdx.x;
  if (bx < 3072) {
    int tz = bx >> 10, blk = bx & 1023;
    const float* src = tz == 0 ? Qin : tz == 1 ? Kin : Vin;
    bf16* dst = tz == 0 ? Qbf : tz == 1 ? Kbf : Vbf;
#pragma unroll
    for (int i = 0; i < 4; ++i) {
      int idx = blk * 1024 + i * 256 + t;  // float4 index
      float4 v = ((const float4*)src)[idx];
      union { bf16 b[4]; uint2 u; } tmp;
      tmp.b[0] = __float2bfloat16(v.x);
      tmp.b[1] = __float2bfloat16(v.y);
      tmp.b[2] = __float2bfloat16(v.z);
      tmp.b[3] = __float2bfloat16(v.w);
      ((uint2*)dst)[idx] = tmp.u;
    }
  } else if (bx < 4096) {
    int idx = bx - 3072;
    int z = idx >> 8;
    const float* W = z == 0 ? Wq : z == 1 ? Wk : z == 2 ? Wv : Wo;
    bf16* T = z == 0 ? WqT : z == 1 ? WkT : z == 2 ? WvT : WoT;
    int tk = (idx & 15) * 64, tn = ((idx >> 4) & 15) * 64;
    int c = t & 63, r0 = t >> 6;
#pragma unroll
    for (int i = 0; i < 16; ++i) {
      int r = i * 4 + r0;
      tile[r][c] = W[(size_t)(tk + r) * nD + tn + c];
    }
    __syncthreads();
#pragma unroll
    for (int i = 0; i < 16; ++i) {
      int r = i * 4 + r0;
      T[(size_t)(tn + r) * nD + tk + c] = __float2bfloat16(tile[c][r]);
    }
  } else {
    int base = (bx - 4096) * 1024 + t * 4;
#pragma unroll
    for (int i = 0; i < 4; ++i) {
      int e = base + i;
      int s = e >> 5, j = e & 31;
      float inv_freq = powf(100000.0f, -(float)(2 * j) / 64.0f);
      float g = (float)s * inv_freq;
      cos_t[e] = __float2bfloat16(cosf(g));
      sin_t[e] = __float2bfloat16(sinf(g));
    }
  }
}

// ---------------------------------------------------------------- fused projection GEMM v6: m97-faithful + 4 blocks/CU.
__global__ __launch_bounds__(256, 4) void gemm_qkv_kernel(
    const bf16* __restrict__ A0, const bf16* __restrict__ A1, const bf16* __restrict__ A2,
    const bf16* __restrict__ Bt0, const bf16* __restrict__ Bt1, const bf16* __restrict__ Bt2,
    bf16* __restrict__ q_h, bf16* __restrict__ k_h, bf16* __restrict__ vt_h,
    const bf16* __restrict__ cos_t, const bf16* __restrict__ sin_t) {
  const int bid = blockIdx.x;
  const int swz = (bid & 7) * 96 + (bid >> 3);
  const int z = swz >> 8;            // 0..2
  const int rem = swz & 255;
  const int n0 = (rem >> 5) * 128;   // 8 n-tiles
  const int m0 = (rem & 31) * 128;   // 32 m-tiles

  const bf16* __restrict__ A  = z == 0 ? A0 : (z == 1 ? A1 : A2);
  const bf16* __restrict__ Bt = z == 0 ? Bt0 : (z == 1 ? Bt1 : Bt2);

  __shared__ bf16 As[128 * 64];   // 16 KiB
  __shared__ bf16 Bs[128 * 64];   // 16 KiB

  const int t = threadIdx.x;          // 0..255
  const int lane = t & 63;
  const int wid = t >> 6;             // 0..3
  const int quad = lane >> 4;
  const int l16 = lane & 15;
  const int r7 = l16 & 7;
  const int wm = wid >> 1;            // 0..1 -> 64 rows each
  const int wn = wid & 1;             // 0..1 -> 64 cols each (one head per wave)

  const int srow = t >> 3;                       // 0..31
  const int scg8 = ((t & 7) ^ (srow & 7)) * 8;   // swizzled k-offset (elements)

  const int ch0 = (quad ^ r7) * 8;
  const int ch1 = ch0 ^ 32;
  const int arow = (wm * 64 + l16) * 64;   // + mi*1024
  const int brow = (wn * 64 + l16) * 64;   // + ni*1024

  float4v acc[4][4] = {};

  for (int T = 0; T < 16; ++T) {
    {
      const bf16* ag_ = A + (size_t)(m0 + srow) * nD + T * 64 + scg8;
      const bf16* bg_ = Bt + (size_t)(n0 + srow) * nD + T * 64 + scg8;
#pragma unroll
      for (int i = 0; i < 4; ++i) {
        gload_lds16(ag_ + (size_t)(i * 32) * nD, As + i * 2048 + wid * 512);
        gload_lds16(bg_ + (size_t)(i * 32) * nD, Bs + i * 2048 + wid * 512);
      }
    }
    asm volatile("s_waitcnt vmcnt(0)" ::: "memory");
    __builtin_amdgcn_s_barrier();

    // ---- kk0 half
    Frag16B fa[4], fb[4];
#pragma unroll
    for (int mi = 0; mi < 4; ++mi) fa[mi].u4 = *(const uint4*)&As[arow + mi * 1024 + ch0];
#pragma unroll
    for (int ni = 0; ni < 4; ++ni) fb[ni].u4 = *(const uint4*)&Bs[brow + ni * 1024 + ch0];
    __builtin_amdgcn_s_setprio(1);
#pragma unroll
    for (int mi = 0; mi < 4; ++mi)
#pragma unroll
      for (int ni = 0; ni < 4; ++ni)
        acc[mi][ni] = __builtin_amdgcn_mfma_f32_16x16x32_bf16(fa[mi].v, fb[ni].v, acc[mi][ni], 0, 0, 0);
    __builtin_amdgcn_s_setprio(0);

    // ---- kk1 half
#pragma unroll
    for (int mi = 0; mi < 4; ++mi) fa[mi].u4 = *(const uint4*)&As[arow + mi * 1024 + ch1];
#pragma unroll
    for (int ni = 0; ni < 4; ++ni) fb[ni].u4 = *(const uint4*)&Bs[brow + ni * 1024 + ch1];
    __builtin_amdgcn_s_setprio(1);
#pragma unroll
    for (int mi = 0; mi < 4; ++mi)
#pragma unroll
      for (int ni = 0; ni < 4; ++ni)
        acc[mi][ni] = __builtin_amdgcn_mfma_f32_16x16x32_bf16(fa[mi].v, fb[ni].v, acc[mi][ni], 0, 0, 0);
    __builtin_amdgcn_s_setprio(0);

    __builtin_amdgcn_s_barrier();
  }

  // ---- epilogue: RoPE + RMSNorm (q,k) or transposed store (v)
  const int col0 = n0 + wn * 64;   // multiple of 64 -> one head per wave
  if (z <= 1) {
    bf16* dst = z ? k_h : q_h;
#pragma unroll
    for (int mi = 0; mi < 4; ++mi)
#pragma unroll
      for (int r = 0; r < 4; ++r) {
        int row = m0 + wm * 64 + mi * 16 + quad * 4 + r;
        int s = row & (nS - 1);
        float x0 = acc[mi][0][r], x1 = acc[mi][1][r], x2 = acc[mi][2][r], x3 = acc[mi][3][r];
        float y[4];
#pragma unroll
        for (int p = 0; p < 2; ++p) {
          int d = p * 16 + l16;
          float c = __bfloat162float(cos_t[s * 32 + d]);
          float sn = __bfloat162float(sin_t[s * 32 + d]);
          float xa = p ? x1 : x0, xb = p ? x3 : x2;
          y[p] = xa * c + xb * sn;
          y[p + 2] = xb * c - xa * sn;
        }
        float ss = y[0] * y[0] + y[1] * y[1] + y[2] * y[2] + y[3] * y[3];
#pragma unroll
        for (int m = 1; m <= 8; m <<= 1) ss += __shfl_xor(ss, m, 64);
        float inv = 1.0f / sqrtf(ss * (1.0f / 64.0f) + 1e-9f);
        if (z == 0) inv *= SC;   // fold attention scale*log2e into Q (f32-exact)
#pragma unroll
        for (int ni = 0; ni < 4; ++ni)
          dst[(size_t)row * nD + col0 + ni * 16 + l16] = __float2bfloat16(y[ni] * inv);
      }
  } else {
    // V: write transposed -> vt_h [b][h][d][s]
#pragma unroll
    for (int mi = 0; mi < 4; ++mi)
#pragma unroll
      for (int r = 0; r < 4; ++r) {
        int row = m0 + wm * 64 + mi * 16 + quad * 4 + r;
        int b = row >> 11, s = row & (nS - 1);
#pragma unroll
        for (int ni = 0; ni < 4; ++ni) {
          int col = col0 + ni * 16 + l16;
          int h = col >> 6, d = col & 63;
          vt_h[((size_t)((b * nH + h) * 64 + d)) * nS + s] = __float2bfloat16(acc[mi][ni][r]);
        }
      }
  }
}

// ---------------------------------------------------------------- output GEMM v3 (round-14 config): 64x128 tile,
// BK=64, double-buffered 48 KiB LDS, ONE barrier per K-step, 3 blocks/CU.
__global__ __launch_bounds__(256, 3) void gemm_out_kernel(
    const bf16* __restrict__ A, const bf16* __restrict__ Bt, float* __restrict__ C) {
  __shared__ bf16 As[2 * 64 * 64];    // 16 KiB
  __shared__ bf16 Bs[2 * 128 * 64];   // 32 KiB
  const int bid = blockIdx.x;         // 0..511
  const int n0 = (bid & 7) * 128;
  const int m0 = (bid >> 3) * 64;
  const int t = threadIdx.x;
  const int lane = t & 63;
  const int wid = t >> 6;
  const int quad = lane >> 4;
  const int l16 = lane & 15;
  const int r7 = l16 & 7;
  const int wm = wid >> 1;
  const int wn = wid & 1;

  const int srow = t >> 3;                       // 0..31
  const int scg8 = ((t & 7) ^ (srow & 7)) * 8;

  const int ch0 = (quad ^ r7) * 8;
  const int ch1 = ch0 ^ 32;
  const int arow = (wm * 32 + l16) * 64;   // + mi*1024 (+buf)
  const int brow = (wn * 64 + l16) * 64;   // + ni*1024 (+buf)

#define STAGE_O(KT, AB, BB) do { \
    const bf16* ag_ = A + (size_t)(m0 + srow) * nD + (KT) * 64 + scg8; \
    const bf16* bg_ = Bt + (size_t)(n0 + srow) * nD + (KT) * 64 + scg8; \
    gload_lds16(ag_, As + (AB) + wid * 512); \
    gload_lds16(ag_ + (size_t)32 * nD, As + (AB) + 2048 + wid * 512); \
    _Pragma("unroll") \
    for (int i = 0; i < 4; ++i) \
      gload_lds16(bg_ + (size_t)(i * 32) * nD, Bs + (BB) + i * 2048 + wid * 512); \
  } while (0)

  float4v acc[2][4] = {};

  STAGE_O(0, 0, 0);
  asm volatile("s_waitcnt vmcnt(0)" ::: "memory");
  __builtin_amdgcn_s_barrier();

#pragma unroll 2
  for (int T = 0; T < 16; ++T) {
    const int cua = (T & 1) * 4096;
    const int cub = (T & 1) * 8192;

    if (T < 15) STAGE_O(T + 1, cua ^ 4096, cub ^ 8192);

    Frag16B a0[2], a1[2], b0[4], b1[4];
#pragma unroll
    for (int mi = 0; mi < 2; ++mi) {
      a0[mi].u4 = *(const uint4*)&As[cua + arow + mi * 1024 + ch0];
      a1[mi].u4 = *(const uint4*)&As[cua + arow + mi * 1024 + ch1];
    }
#pragma unroll
    for (int ni = 0; ni < 4; ++ni) {
      b0[ni].u4 = *(const uint4*)&Bs[cub + brow + ni * 1024 + ch0];
      b1[ni].u4 = *(const uint4*)&Bs[cub + brow + ni * 1024 + ch1];
    }

    __builtin_amdgcn_s_setprio(1);
#pragma unroll
    for (int mi = 0; mi < 2; ++mi)
#pragma unroll
      for (int ni = 0; ni < 4; ++ni)
        acc[mi][ni] = __builtin_amdgcn_mfma_f32_16x16x32_bf16(a0[mi].v, b0[ni].v, acc[mi][ni], 0, 0, 0);
#pragma unroll
    for (int mi = 0; mi < 2; ++mi)
#pragma unroll
      for (int ni = 0; ni < 4; ++ni)
        acc[mi][ni] = __builtin_amdgcn_mfma_f32_16x16x32_bf16(a1[mi].v, b1[ni].v, acc[mi][ni], 0, 0, 0);
    __builtin_amdgcn_s_setprio(0);

    asm volatile("s_waitcnt vmcnt(0)" ::: "memory");
    __builtin_amdgcn_s_barrier();
  }
#undef STAGE_O

#pragma unroll
  for (int mi = 0; mi < 2; ++mi)
#pragma unroll
    for (int ni = 0; ni < 4; ++ni)
#pragma unroll
      for (int r = 0; r < 4; ++r) {
        int row = m0 + wm * 32 + mi * 16 + quad * 4 + r;
        int col = n0 + wn * 64 + ni * 16 + l16;
        C[(size_t)row * nD + col] = acc[mi][ni][r];
      }
}

// ---------------------------------------------------------------- flash attention v11: 4-wave 256-thread blocks,
// 64-row q-tiles, grid 1024, LPT, XCD-pinned heads, 4 blocks/CU. T14 async-STAGE split:
// tile kt+1 is loaded into REGISTERS right after the write-barrier and stays in flight across the
// whole compute phase; regs are ds_written to LDS (linear, conflict-free) at the next iteration top
// (compiler inserts the vmcnt before the write). Same LDS layout/reads as v10. Q pre-scaled by SC;
// l via MFMA ones-trick.
__global__ __launch_bounds__(256, 4) void attn_kernel(const bf16* __restrict__ q_h,
                                                      const bf16* __restrict__ k_h,
                                                      const bf16* __restrict__ vt_h,
                                                      bf16* __restrict__ vals) {
  __shared__ bf16 lds_buf[16384];      // [K: 0..8191 | V_HB0: 8192..12287 | V_HB1: 12288..16383]

  const int t = threadIdx.x;           // 0..255
  const int lane = t & 63, wid = t >> 6, quad = lane >> 4, l16 = lane & 15;
  const int id = blockIdx.x;           // 0..1023
  const int xcd = id & 7;
  const int j = id >> 3;               // 0..127
  const int bh = xcd * 4 + (j & 3);    // head pinned to XCD
  const int qt = 31 - (j >> 2);        // 64-row q-tile index, LPT: longest first
  const int b = bh >> 4, h = bh & 15;

  const int nfull = qt >> 1;           // full unmasked 128-key tiles

  const bf16* Kbase = k_h + ((size_t)b * nS) * nD + h * 64;
  const bf16* Vbase = vt_h + (size_t)bh * 64 * nS;  // [d][s]

  const int rl = lane >> 3;               // 0..7
  const int cg8 = ((lane & 7) ^ rl) * 8;  // pre-swizzled source chunk (elem offset)
  const int r7 = l16 & 7;

  bf16* const scratch = lds_buf + wid * 1152;  // 16 x 72 per wave (epilogue only)

  const int q0w = qt * 64 + wid * 16;     // wave's first q row

  const short4v vones = {(short)0x3F80, (short)0x3F80, (short)0x3F80, (short)0x3F80};  // bf16 1.0 x4

  // Q B-frags (col=q=l16, k=d), 2 d-halves
  Frag16B qf[2];
  {
    const bf16* qp = q_h + ((size_t)(b * nS + q0w + l16)) * nD + h * 64;
    qf[0].u4 = *(const uint4*)(qp + quad * 8);
    qf[1].u4 = *(const uint4*)(qp + 32 + quad * 8);
  }

  uint4 kreg[4], vreg[4];

  // load 128-key K/V tile KT into registers (same source addresses as v10's gload_lds)
#define LOAD_KV(KT) do { \
    const bf16* kg_ = Kbase + (size_t)((KT) * 128 + wid * 32 + rl) * nD + cg8; \
    kreg[0] = *(const uint4*)(kg_); \
    kreg[1] = *(const uint4*)(kg_ + (size_t)8 * nD); \
    kreg[2] = *(const uint4*)(kg_ + (size_t)16 * nD); \
    kreg[3] = *(const uint4*)(kg_ + (size_t)24 * nD); \
    const bf16* vg_ = Vbase + (size_t)(wid * 16 + rl) * nS + (KT) * 128 + cg8; \
    vreg[0] = *(const uint4*)(vg_); \
    vreg[1] = *(const uint4*)(vg_ + 64); \
    vreg[2] = *(const uint4*)(vg_ + (size_t)8 * nS); \
    vreg[3] = *(const uint4*)(vg_ + (size_t)8 * nS + 64); \
  } while (0)

  // write registers -> LDS; dest = wave base + lane*16B (linear, conflict-free); layout == v10
#define WRITE_KV() do { \
    *(uint4*)&lds_buf[wid * 2048 + lane * 8] = kreg[0]; \
    *(uint4*)&lds_buf[wid * 2048 + 512 + lane * 8] = kreg[1]; \
    *(uint4*)&lds_buf[wid * 2048 + 1024 + lane * 8] = kreg[2]; \
    *(uint4*)&lds_buf[wid * 2048 + 1536 + lane * 8] = kreg[3]; \
    *(uint4*)&lds_buf[8192 + wid * 1024 + lane * 8] = vreg[0]; \
    *(uint4*)&lds_buf[12288 + wid * 1024 + lane * 8] = vreg[1]; \
    *(uint4*)&lds_buf[8192 + wid * 1024 + 512 + lane * 8] = vreg[2]; \
    *(uint4*)&lds_buf[12288 + wid * 1024 + 512 + lane * 8] = vreg[3]; \
  } while (0)

  // QK^T for half HB of the staged tile -> ST (S^T frags, key=row)
#define QKH(HB, ST) do { \
    _Pragma("unroll") \
    for (int kt4 = 0; kt4 < 4; ++kt4) { \
      int row = (HB) * 64 + kt4 * 16 + l16; \
      Frag16B k0_, k1_; \
      k0_.u4 = *(const uint4*)&lds_buf[row * 64 + ((quad ^ r7) * 8)]; \
      k1_.u4 = *(const uint4*)&lds_buf[row * 64 + (((quad + 4) ^ r7) * 8)]; \
      float4v zz_ = {}; \
      zz_ = __builtin_amdgcn_mfma_f32_16x16x32_bf16(k0_.v, qf[0].v, zz_, 0, 0, 0); \
      (ST)[kt4] = __builtin_amdgcn_mfma_f32_16x16x32_bf16(k1_.v, qf[1].v, zz_, 0, 0, 0); \
    } \
  } while (0)

  // exp (unmasked) ST -> PF (Q pre-scaled; l via ones-trick in PVH)
#define EXPH(ST, PF) do { \
    _Pragma("unroll") \
    for (int kt4 = 0; kt4 < 4; ++kt4) \
      _Pragma("unroll") \
      for (int r = 0; r < 4; ++r) { \
        float p_ = fast_exp2((ST)[kt4][r]); \
        union { bf16 hh; short ss; } cv_; \
        cv_.hh = __float2bfloat16(p_); \
        (PF)[kt4][r] = cv_.ss; \
      } \
  } while (0)

  // exp (masked, diagonal tile) for half HB of tile nfull
#define EXPHM(ST, PF, HB) do { \
    int qg_ = q0w + l16; \
    _Pragma("unroll") \
    for (int kt4 = 0; kt4 < 4; ++kt4) { \
      int key0_ = nfull * 128 + (HB) * 64 + kt4 * 16 + quad * 4; \
      _Pragma("unroll") \
      for (int r = 0; r < 4; ++r) { \
        float x_ = (ST)[kt4][r]; \
        if (key0_ + r > qg_) x_ = -12000.0f; \
        float p_ = fast_exp2(x_); \
        union { bf16 hh; short ss; } cv_; \
        cv_.hh = __float2bfloat16(p_); \
        (PF)[kt4][r] = cv_.ss; \
      } \
    } \
  } while (0)

  // O^T += V^T(half HB) . P^T ; l-row via ones MFMA
#define PVH(HB, PF) do { \
    const bf16* Vb_ = lds_buf + 8192 + (HB) * 4096; \
    _Pragma("unroll") \
    for (int dt = 0; dt < 4; ++dt) { \
      int row = dt * 16 + l16; \
      _Pragma("unroll") \
      for (int kt4 = 0; kt4 < 4; ++kt4) { \
        int chunk_ = kt4 * 2 + (quad >> 1); \
        union { uint2 u; short4v s; } vv_; \
        vv_.u = *(const uint2*)&Vb_[row * 64 + ((chunk_ ^ r7) * 8) + (quad & 1) * 4]; \
        o_acc[dt] = __builtin_amdgcn_mfma_f32_16x16x16bf16_1k(vv_.s, (PF)[kt4], o_acc[dt], 0, 0, 0); \
      } \
    } \
    _Pragma("unroll") \
    for (int kt4 = 0; kt4 < 4; ++kt4) \
      o_l = __builtin_amdgcn_mfma_f32_16x16x16bf16_1k(vones, (PF)[kt4], o_l, 0, 0, 0); \
  } while (0)

  float4v o_acc[4] = {};
  float4v o_l = {};

  LOAD_KV(0);   // prologue: tile 0 -> regs (compiler inserts vmcnt before first WRITE_KV)

  for (int kt = 0; kt <= nfull; ++kt) {
    WRITE_KV();      // regs (tile kt) -> LDS
    lds_barrier();   // all writes visible to all waves

    if (kt < nfull) LOAD_KV(kt + 1);   // prefetch next tile; in flight across compute

    float4v st[4];
    short4v pf[4];
    if (kt < nfull) {
      // full unmasked tile
      __builtin_amdgcn_s_setprio(1);
      QKH(0, st);
      __builtin_amdgcn_s_setprio(0);
      EXPH(st, pf);
      __builtin_amdgcn_s_setprio(1);
      PVH(0, pf);
      QKH(1, st);
      __builtin_amdgcn_s_setprio(0);
      EXPH(st, pf);
      __builtin_amdgcn_s_setprio(1);
      PVH(1, pf);
      __builtin_amdgcn_s_setprio(0);
    } else if (qt & 1) {
      QKH(0, st);
      EXPH(st, pf);      // keys all <= q rows -> unmasked
      PVH(0, pf);
      QKH(1, st);
      EXPHM(st, pf, 1);  // diagonal
      PVH(1, pf);
    } else {
      QKH(0, st);
      EXPHM(st, pf, 0);  // diagonal
      PVH(0, pf);
      // HB1 keys all > q rows -> fully masked -> skip (block-uniform)
    }

    lds_barrier();   // all reads done before next iteration's writes
  }
#undef LOAD_KV
#undef WRITE_KV
#undef QKH
#undef EXPH
#undef EXPHM
#undef PVH

  // ---- epilogue: LDS-transpose, coalesced 16B stores (l complete per-lane in o_l[0])
  float inv_l = 1.0f / o_l[0];
#pragma unroll
  for (int dt = 0; dt < 4; ++dt) {
    union { bf16 b2[2]; uint u; } p01, p23;
    p01.b2[0] = __float2bfloat16(o_acc[dt][0] * inv_l);
    p01.b2[1] = __float2bfloat16(o_acc[dt][1] * inv_l);
    p23.b2[0] = __float2bfloat16(o_acc[dt][2] * inv_l);
    p23.b2[1] = __float2bfloat16(o_acc[dt][3] * inv_l);
    *(uint*)&scratch[l16 * 72 + dt * 16 + quad * 4] = p01.u;
    *(uint*)&scratch[l16 * 72 + dt * 16 + quad * 4 + 2] = p23.u;
  }
  lgkm_wait();  // own writes visible to own reads
  uint4 r0 = *(const uint4*)&scratch[l16 * 72 + quad * 16];
  uint4 r1 = *(const uint4*)&scratch[l16 * 72 + quad * 16 + 8];
  int qrow = q0w + l16;
  bf16* vp = vals + ((size_t)(b * nS + qrow)) * nD + h * 64 + quad * 16;
  *(uint4*)(vp) = r0;
  *(uint4*)(vp + 8) = r1;
}

// ---------------------------------------------------------------- launch
extern "C" void kernel_launch(void* const* d_in, const int* in_sizes, int n_in,
                              void* d_out, int out_size, void* d_ws, size_t ws_size,
                              hipStream_t stream) {
  const float* Qin = (const float*)d_in[0];
  const float* Kin = (const float*)d_in[1];
  const float* Vin = (const float*)d_in[2];
  const float* Wq = (const float*)d_in[4];
  const float* Wk = (const float*)d_in[5];
  const float* Wv = (const float*)d_in[6];
  const float* Wo = (const float*)d_in[7];
  float* out = (float*)d_out;

  char* ws = (char*)d_ws;
  const size_t MB = 1u << 20;
  bf16* Qbf = (bf16*)(ws + 0 * MB);
  bf16* Kbf = (bf16*)(ws + 8 * MB);
  bf16* Vbf = (bf16*)(ws + 16 * MB);
  bf16* WqT = (bf16*)(ws + 24 * MB);
  bf16* WkT = (bf16*)(ws + 26 * MB);
  bf16* WvT = (bf16*)(ws + 28 * MB);
  bf16* WoT = (bf16*)(ws + 30 * MB);
  bf16* cos_t = (bf16*)(ws + 32 * MB);
  bf16* sin_t = (bf16*)(ws + 33 * MB);
  bf16* q_h = (bf16*)(ws + 34 * MB);
  bf16* k_h = (bf16*)(ws + 42 * MB);
  bf16* vt_h = (bf16*)(ws + 50 * MB);
  bf16* vals = (bf16*)(ws + 58 * MB);

  prep_kernel<<<4160, 256, 0, stream>>>(Qin, Kin, Vin, Wq, Wk, Wv, Wo,
                                        Qbf, Kbf, Vbf, WqT, WkT, WvT, WoT, cos_t, sin_t);

  gemm_qkv_kernel<<<768, 256, 0, stream>>>(Qbf, Kbf, Vbf, WqT, WkT, WvT,
                                           q_h, k_h, vt_h, cos_t, sin_t);

  attn_kernel<<<1024, 256, 0, stream>>>(q_h, k_h, vt_h, vals);

  gemm_out_kernel<<<512, 256, 0, stream>>>(vals, WoT, out);
}

// Round 17
// 204.532 us; speedup vs baseline: 1.3366x; 1.3366x over previous
//
#include <hip/hip_runtime.h>
#include <hip/hip_bf16.h>
#include <stdint.h>

typedef __hip_bfloat16 bf16;
typedef __attribute__((ext_vector_type(8))) short short8;
typedef __attribute__((ext_vector_type(4))) short short4v;
typedef __attribute__((ext_vector_type(4))) float float4v;

static constexpr int nB = 2, nS = 2048, nD = 1024, nH = 16, nHD = 64;
static constexpr int nBS = nB * nS;   // 4096

#define AS_GLOBAL __attribute__((address_space(1)))
#define AS_LDS    __attribute__((address_space(3)))

union Frag16B { short8 v; uint4 u4; uint2 u2[2]; };

__device__ __forceinline__ void gload_lds16(const void* g, void* l) {
  __builtin_amdgcn_global_load_lds((AS_GLOBAL uint32_t*)(g), (AS_LDS uint32_t*)(l), 16, 0, 0);
}

__device__ __forceinline__ float fast_exp2(float x) {
#if __has_builtin(__builtin_amdgcn_exp2f)
  return __builtin_amdgcn_exp2f(x);
#else
  float r; asm volatile("v_exp_f32 %0, %1" : "=v"(r) : "v"(x)); return r;
#endif
}

// drain LDS ops but NOT vmem: prefetch global loads stay in flight across the barrier
__device__ __forceinline__ void lds_barrier() {
  asm volatile("s_waitcnt lgkmcnt(0)\ns_barrier" ::: "memory");
}

__device__ __forceinline__ void lgkm_wait() {
  asm volatile("s_waitcnt lgkmcnt(0)" ::: "memory");
}

static constexpr float SC = 0.18033688011112042f;  // 0.125 * log2(e), folded into Q at projection

// ---------------------------------------------------------------- prep: cast QKV->bf16, W->W^T bf16, rope tables
__global__ __launch_bounds__(256) void prep_kernel(
    const float* __restrict__ Qin, const float* __restrict__ Kin, const float* __restrict__ Vin,
    const float* __restrict__ Wq, const float* __restrict__ Wk,
    const float* __restrict__ Wv, const float* __restrict__ Wo,
    bf16* __restrict__ Qbf, bf16* __restrict__ Kbf, bf16* __restrict__ Vbf,
    bf16* __restrict__ WqT, bf16* __restrict__ WkT, bf16* __restrict__ WvT, bf16* __restrict__ WoT,
    bf16* __restrict__ cos_t, bf16* __restrict__ sin_t) {
  __shared__ float tile[64][65];
  int bx = blockIdx.x, t = threadIdx.x;
  if (bx < 3072) {
    int tz = bx >> 10, blk = bx & 1023;
    const float* src = tz == 0 ? Qin : tz == 1 ? Kin : Vin;
    bf16* dst = tz == 0 ? Qbf : tz == 1 ? Kbf : Vbf;
#pragma unroll
    for (int i = 0; i < 4; ++i) {
      int idx = blk * 1024 + i * 256 + t;  // float4 index
      float4 v = ((const float4*)src)[idx];
      union { bf16 b[4]; uint2 u; } tmp;
      tmp.b[0] = __float2bfloat16(v.x);
      tmp.b[1] = __float2bfloat16(v.y);
      tmp.b[2] = __float2bfloat16(v.z);
      tmp.b[3] = __float2bfloat16(v.w);
      ((uint2*)dst)[idx] = tmp.u;
    }
  } else if (bx < 4096) {
    int idx = bx - 3072;
    int z = idx >> 8;
    const float* W = z == 0 ? Wq : z == 1 ? Wk : z == 2 ? Wv : Wo;
    bf16* T = z == 0 ? WqT : z == 1 ? WkT : z == 2 ? WvT : WoT;
    int tk = (idx & 15) * 64, tn = ((idx >> 4) & 15) * 64;
    int c = t & 63, r0 = t >> 6;
#pragma unroll
    for (int i = 0; i < 16; ++i) {
      int r = i * 4 + r0;
      tile[r][c] = W[(size_t)(tk + r) * nD + tn + c];
    }
    __syncthreads();
#pragma unroll
    for (int i = 0; i < 16; ++i) {
      int r = i * 4 + r0;
      T[(size_t)(tn + r) * nD + tk + c] = __float2bfloat16(tile[c][r]);
    }
  } else {
    int base = (bx - 4096) * 1024 + t * 4;
#pragma unroll
    for (int i = 0; i < 4; ++i) {
      int e = base + i;
      int s = e >> 5, j = e & 31;
      float inv_freq = powf(100000.0f, -(float)(2 * j) / 64.0f);
      float g = (float)s * inv_freq;
      cos_t[e] = __float2bfloat16(cosf(g));
      sin_t[e] = __float2bfloat16(sinf(g));
    }
  }
}

// ---------------------------------------------------------------- fused projection GEMM v6: m97-faithful + 4 blocks/CU.
__global__ __launch_bounds__(256, 4) void gemm_qkv_kernel(
    const bf16* __restrict__ A0, const bf16* __restrict__ A1, const bf16* __restrict__ A2,
    const bf16* __restrict__ Bt0, const bf16* __restrict__ Bt1, const bf16* __restrict__ Bt2,
    bf16* __restrict__ q_h, bf16* __restrict__ k_h, bf16* __restrict__ vt_h,
    const bf16* __restrict__ cos_t, const bf16* __restrict__ sin_t) {
  const int bid = blockIdx.x;
  const int swz = (bid & 7) * 96 + (bid >> 3);
  const int z = swz >> 8;            // 0..2
  const int rem = swz & 255;
  const int n0 = (rem >> 5) * 128;   // 8 n-tiles
  const int m0 = (rem & 31) * 128;   // 32 m-tiles

  const bf16* __restrict__ A  = z == 0 ? A0 : (z == 1 ? A1 : A2);
  const bf16* __restrict__ Bt = z == 0 ? Bt0 : (z == 1 ? Bt1 : Bt2);

  __shared__ bf16 As[128 * 64];   // 16 KiB
  __shared__ bf16 Bs[128 * 64];   // 16 KiB

  const int t = threadIdx.x;          // 0..255
  const int lane = t & 63;
  const int wid = t >> 6;             // 0..3
  const int quad = lane >> 4;
  const int l16 = lane & 15;
  const int r7 = l16 & 7;
  const int wm = wid >> 1;            // 0..1 -> 64 rows each
  const int wn = wid & 1;             // 0..1 -> 64 cols each (one head per wave)

  const int srow = t >> 3;                       // 0..31
  const int scg8 = ((t & 7) ^ (srow & 7)) * 8;   // swizzled k-offset (elements)

  const int ch0 = (quad ^ r7) * 8;
  const int ch1 = ch0 ^ 32;
  const int arow = (wm * 64 + l16) * 64;   // + mi*1024
  const int brow = (wn * 64 + l16) * 64;   // + ni*1024

  float4v acc[4][4] = {};

  for (int T = 0; T < 16; ++T) {
    {
      const bf16* ag_ = A + (size_t)(m0 + srow) * nD + T * 64 + scg8;
      const bf16* bg_ = Bt + (size_t)(n0 + srow) * nD + T * 64 + scg8;
#pragma unroll
      for (int i = 0; i < 4; ++i) {
        gload_lds16(ag_ + (size_t)(i * 32) * nD, As + i * 2048 + wid * 512);
        gload_lds16(bg_ + (size_t)(i * 32) * nD, Bs + i * 2048 + wid * 512);
      }
    }
    asm volatile("s_waitcnt vmcnt(0)" ::: "memory");
    __builtin_amdgcn_s_barrier();

    // ---- kk0 half
    Frag16B fa[4], fb[4];
#pragma unroll
    for (int mi = 0; mi < 4; ++mi) fa[mi].u4 = *(const uint4*)&As[arow + mi * 1024 + ch0];
#pragma unroll
    for (int ni = 0; ni < 4; ++ni) fb[ni].u4 = *(const uint4*)&Bs[brow + ni * 1024 + ch0];
    __builtin_amdgcn_s_setprio(1);
#pragma unroll
    for (int mi = 0; mi < 4; ++mi)
#pragma unroll
      for (int ni = 0; ni < 4; ++ni)
        acc[mi][ni] = __builtin_amdgcn_mfma_f32_16x16x32_bf16(fa[mi].v, fb[ni].v, acc[mi][ni], 0, 0, 0);
    __builtin_amdgcn_s_setprio(0);

    // ---- kk1 half
#pragma unroll
    for (int mi = 0; mi < 4; ++mi) fa[mi].u4 = *(const uint4*)&As[arow + mi * 1024 + ch1];
#pragma unroll
    for (int ni = 0; ni < 4; ++ni) fb[ni].u4 = *(const uint4*)&Bs[brow + ni * 1024 + ch1];
    __builtin_amdgcn_s_setprio(1);
#pragma unroll
    for (int mi = 0; mi < 4; ++mi)
#pragma unroll
      for (int ni = 0; ni < 4; ++ni)
        acc[mi][ni] = __builtin_amdgcn_mfma_f32_16x16x32_bf16(fa[mi].v, fb[ni].v, acc[mi][ni], 0, 0, 0);
    __builtin_amdgcn_s_setprio(0);

    __builtin_amdgcn_s_barrier();
  }

  // ---- epilogue: RoPE + RMSNorm (q,k) or transposed store (v)
  const int col0 = n0 + wn * 64;   // multiple of 64 -> one head per wave
  if (z <= 1) {
    bf16* dst = z ? k_h : q_h;
#pragma unroll
    for (int mi = 0; mi < 4; ++mi)
#pragma unroll
      for (int r = 0; r < 4; ++r) {
        int row = m0 + wm * 64 + mi * 16 + quad * 4 + r;
        int s = row & (nS - 1);
        float x0 = acc[mi][0][r], x1 = acc[mi][1][r], x2 = acc[mi][2][r], x3 = acc[mi][3][r];
        float y[4];
#pragma unroll
        for (int p = 0; p < 2; ++p) {
          int d = p * 16 + l16;
          float c = __bfloat162float(cos_t[s * 32 + d]);
          float sn = __bfloat162float(sin_t[s * 32 + d]);
          float xa = p ? x1 : x0, xb = p ? x3 : x2;
          y[p] = xa * c + xb * sn;
          y[p + 2] = xb * c - xa * sn;
        }
        float ss = y[0] * y[0] + y[1] * y[1] + y[2] * y[2] + y[3] * y[3];
#pragma unroll
        for (int m = 1; m <= 8; m <<= 1) ss += __shfl_xor(ss, m, 64);
        float inv = 1.0f / sqrtf(ss * (1.0f / 64.0f) + 1e-9f);
        if (z == 0) inv *= SC;   // fold attention scale*log2e into Q (f32-exact)
#pragma unroll
        for (int ni = 0; ni < 4; ++ni)
          dst[(size_t)row * nD + col0 + ni * 16 + l16] = __float2bfloat16(y[ni] * inv);
      }
  } else {
    // V: write transposed -> vt_h [b][h][d][s]
#pragma unroll
    for (int mi = 0; mi < 4; ++mi)
#pragma unroll
      for (int r = 0; r < 4; ++r) {
        int row = m0 + wm * 64 + mi * 16 + quad * 4 + r;
        int b = row >> 11, s = row & (nS - 1);
#pragma unroll
        for (int ni = 0; ni < 4; ++ni) {
          int col = col0 + ni * 16 + l16;
          int h = col >> 6, d = col & 63;
          vt_h[((size_t)((b * nH + h) * 64 + d)) * nS + s] = __float2bfloat16(acc[mi][ni][r]);
        }
      }
  }
}

// ---------------------------------------------------------------- output GEMM v3: 64x128 tile, BK=64,
// double-buffered 48 KiB LDS, ONE barrier per K-step, 3 blocks/CU.
__global__ __launch_bounds__(256, 3) void gemm_out_kernel(
    const bf16* __restrict__ A, const bf16* __restrict__ Bt, float* __restrict__ C) {
  __shared__ bf16 As[2 * 64 * 64];    // 16 KiB
  __shared__ bf16 Bs[2 * 128 * 64];   // 32 KiB
  const int bid = blockIdx.x;         // 0..511
  const int n0 = (bid & 7) * 128;
  const int m0 = (bid >> 3) * 64;
  const int t = threadIdx.x;
  const int lane = t & 63;
  const int wid = t >> 6;
  const int quad = lane >> 4;
  const int l16 = lane & 15;
  const int r7 = l16 & 7;
  const int wm = wid >> 1;
  const int wn = wid & 1;

  const int srow = t >> 3;                       // 0..31
  const int scg8 = ((t & 7) ^ (srow & 7)) * 8;

  const int ch0 = (quad ^ r7) * 8;
  const int ch1 = ch0 ^ 32;
  const int arow = (wm * 32 + l16) * 64;   // + mi*1024 (+buf)
  const int brow = (wn * 64 + l16) * 64;   // + ni*1024 (+buf)

#define STAGE_O(KT, AB, BB) do { \
    const bf16* ag_ = A + (size_t)(m0 + srow) * nD + (KT) * 64 + scg8; \
    const bf16* bg_ = Bt + (size_t)(n0 + srow) * nD + (KT) * 64 + scg8; \
    gload_lds16(ag_, As + (AB) + wid * 512); \
    gload_lds16(ag_ + (size_t)32 * nD, As + (AB) + 2048 + wid * 512); \
    _Pragma("unroll") \
    for (int i = 0; i < 4; ++i) \
      gload_lds16(bg_ + (size_t)(i * 32) * nD, Bs + (BB) + i * 2048 + wid * 512); \
  } while (0)

  float4v acc[2][4] = {};

  STAGE_O(0, 0, 0);
  asm volatile("s_waitcnt vmcnt(0)" ::: "memory");
  __builtin_amdgcn_s_barrier();

#pragma unroll 2
  for (int T = 0; T < 16; ++T) {
    const int cua = (T & 1) * 4096;
    const int cub = (T & 1) * 8192;

    if (T < 15) STAGE_O(T + 1, cua ^ 4096, cub ^ 8192);

    Frag16B a0[2], a1[2], b0[4], b1[4];
#pragma unroll
    for (int mi = 0; mi < 2; ++mi) {
      a0[mi].u4 = *(const uint4*)&As[cua + arow + mi * 1024 + ch0];
      a1[mi].u4 = *(const uint4*)&As[cua + arow + mi * 1024 + ch1];
    }
#pragma unroll
    for (int ni = 0; ni < 4; ++ni) {
      b0[ni].u4 = *(const uint4*)&Bs[cub + brow + ni * 1024 + ch0];
      b1[ni].u4 = *(const uint4*)&Bs[cub + brow + ni * 1024 + ch1];
    }

    __builtin_amdgcn_s_setprio(1);
#pragma unroll
    for (int mi = 0; mi < 2; ++mi)
#pragma unroll
      for (int ni = 0; ni < 4; ++ni)
        acc[mi][ni] = __builtin_amdgcn_mfma_f32_16x16x32_bf16(a0[mi].v, b0[ni].v, acc[mi][ni], 0, 0, 0);
#pragma unroll
    for (int mi = 0; mi < 2; ++mi)
#pragma unroll
      for (int ni = 0; ni < 4; ++ni)
        acc[mi][ni] = __builtin_amdgcn_mfma_f32_16x16x32_bf16(a1[mi].v, b1[ni].v, acc[mi][ni], 0, 0, 0);
    __builtin_amdgcn_s_setprio(0);

    asm volatile("s_waitcnt vmcnt(0)" ::: "memory");
    __builtin_amdgcn_s_barrier();
  }
#undef STAGE_O

#pragma unroll
  for (int mi = 0; mi < 2; ++mi)
#pragma unroll
    for (int ni = 0; ni < 4; ++ni)
#pragma unroll
      for (int r = 0; r < 4; ++r) {
        int row = m0 + wm * 32 + mi * 16 + quad * 4 + r;
        int col = n0 + wn * 64 + ni * 16 + l16;
        C[(size_t)row * nD + col] = acc[mi][ni][r];
      }
}

// ---------------------------------------------------------------- flash attention v10: 4-wave 256-thread blocks,
// 64-row q-tiles (32 per head) -> grid 1024, LPT (longest first), XCD-pinned heads.
// SINGLE-buffered 32 KiB LDS [K 128x64 | V 2x 64x64], m97-style 2-barrier loop per 128-key tile,
// 4 blocks/CU. Q pre-scaled by SC; l via MFMA ones-trick. (Round-14 best config, verified 199.2 us.)
__global__ __launch_bounds__(256, 4) void attn_kernel(const bf16* __restrict__ q_h,
                                                      const bf16* __restrict__ k_h,
                                                      const bf16* __restrict__ vt_h,
                                                      bf16* __restrict__ vals) {
  __shared__ bf16 lds_buf[16384];      // [K: 0..8191 | V_HB0: 8192..12287 | V_HB1: 12288..16383]

  const int t = threadIdx.x;           // 0..255
  const int lane = t & 63, wid = t >> 6, quad = lane >> 4, l16 = lane & 15;
  const int id = blockIdx.x;           // 0..1023
  const int xcd = id & 7;
  const int j = id >> 3;               // 0..127
  const int bh = xcd * 4 + (j & 3);    // head pinned to XCD
  const int qt = 31 - (j >> 2);        // 64-row q-tile index, LPT: longest first
  const int b = bh >> 4, h = bh & 15;

  const int nfull = qt >> 1;           // full unmasked 128-key tiles

  const bf16* Kbase = k_h + ((size_t)b * nS) * nD + h * 64;
  const bf16* Vbase = vt_h + (size_t)bh * 64 * nS;  // [d][s]

  const int rl = lane >> 3;               // 0..7
  const int cg8 = ((lane & 7) ^ rl) * 8;  // pre-swizzled source chunk (elem offset)
  const int r7 = l16 & 7;

  bf16* const scratch = lds_buf + wid * 1152;  // 16 x 72 per wave (epilogue only)

  const int q0w = qt * 64 + wid * 16;     // wave's first q row

  const short4v vones = {(short)0x3F80, (short)0x3F80, (short)0x3F80, (short)0x3F80};  // bf16 1.0 x4

  // Q B-frags (col=q=l16, k=d), 2 d-halves
  Frag16B qf[2];
  {
    const bf16* qp = q_h + ((size_t)(b * nS + q0w + l16)) * nD + h * 64;
    qf[0].u4 = *(const uint4*)(qp + quad * 8);
    qf[1].u4 = *(const uint4*)(qp + 32 + quad * 8);
  }

  // stage 128-key K/V tile KT into the single buffer: linear LDS dest, swizzled global source.
#define STAGE_KV(KT) do { \
    const bf16* kg_ = Kbase + (size_t)((KT) * 128 + wid * 32 + rl) * nD + cg8; \
    gload_lds16(kg_, lds_buf + wid * 2048); \
    gload_lds16(kg_ + (size_t)8 * nD, lds_buf + wid * 2048 + 512); \
    gload_lds16(kg_ + (size_t)16 * nD, lds_buf + wid * 2048 + 1024); \
    gload_lds16(kg_ + (size_t)24 * nD, lds_buf + wid * 2048 + 1536); \
    const bf16* vg_ = Vbase + (size_t)(wid * 16 + rl) * nS + (KT) * 128 + cg8; \
    gload_lds16(vg_, lds_buf + 8192 + wid * 1024); \
    gload_lds16(vg_ + 64, lds_buf + 12288 + wid * 1024); \
    gload_lds16(vg_ + (size_t)8 * nS, lds_buf + 8192 + wid * 1024 + 512); \
    gload_lds16(vg_ + (size_t)8 * nS + 64, lds_buf + 12288 + wid * 1024 + 512); \
  } while (0)

  // QK^T for half HB of the staged tile -> ST (S^T frags, key=row)
#define QKH(HB, ST) do { \
    _Pragma("unroll") \
    for (int kt4 = 0; kt4 < 4; ++kt4) { \
      int row = (HB) * 64 + kt4 * 16 + l16; \
      Frag16B k0_, k1_; \
      k0_.u4 = *(const uint4*)&lds_buf[row * 64 + ((quad ^ r7) * 8)]; \
      k1_.u4 = *(const uint4*)&lds_buf[row * 64 + (((quad + 4) ^ r7) * 8)]; \
      float4v zz_ = {}; \
      zz_ = __builtin_amdgcn_mfma_f32_16x16x32_bf16(k0_.v, qf[0].v, zz_, 0, 0, 0); \
      (ST)[kt4] = __builtin_amdgcn_mfma_f32_16x16x32_bf16(k1_.v, qf[1].v, zz_, 0, 0, 0); \
    } \
  } while (0)

  // exp (unmasked) ST -> PF (Q pre-scaled; l via ones-trick in PVH)
#define EXPH(ST, PF) do { \
    _Pragma("unroll") \
    for (int kt4 = 0; kt4 < 4; ++kt4) \
      _Pragma("unroll") \
      for (int r = 0; r < 4; ++r) { \
        float p_ = fast_exp2((ST)[kt4][r]); \
        union { bf16 hh; short ss; } cv_; \
        cv_.hh = __float2bfloat16(p_); \
        (PF)[kt4][r] = cv_.ss; \
      } \
  } while (0)

  // exp (masked, diagonal tile) for half HB of tile nfull
#define EXPHM(ST, PF, HB) do { \
    int qg_ = q0w + l16; \
    _Pragma("unroll") \
    for (int kt4 = 0; kt4 < 4; ++kt4) { \
      int key0_ = nfull * 128 + (HB) * 64 + kt4 * 16 + quad * 4; \
      _Pragma("unroll") \
      for (int r = 0; r < 4; ++r) { \
        float x_ = (ST)[kt4][r]; \
        if (key0_ + r > qg_) x_ = -12000.0f; \
        float p_ = fast_exp2(x_); \
        union { bf16 hh; short ss; } cv_; \
        cv_.hh = __float2bfloat16(p_); \
        (PF)[kt4][r] = cv_.ss; \
      } \
    } \
  } while (0)

  // O^T += V^T(half HB) . P^T ; l-row via ones MFMA
#define PVH(HB, PF) do { \
    const bf16* Vb_ = lds_buf + 8192 + (HB) * 4096; \
    _Pragma("unroll") \
    for (int dt = 0; dt < 4; ++dt) { \
      int row = dt * 16 + l16; \
      _Pragma("unroll") \
      for (int kt4 = 0; kt4 < 4; ++kt4) { \
        int chunk_ = kt4 * 2 + (quad >> 1); \
        union { uint2 u; short4v s; } vv_; \
        vv_.u = *(const uint2*)&Vb_[row * 64 + ((chunk_ ^ r7) * 8) + (quad & 1) * 4]; \
        o_acc[dt] = __builtin_amdgcn_mfma_f32_16x16x16bf16_1k(vv_.s, (PF)[kt4], o_acc[dt], 0, 0, 0); \
      } \
    } \
    _Pragma("unroll") \
    for (int kt4 = 0; kt4 < 4; ++kt4) \
      o_l = __builtin_amdgcn_mfma_f32_16x16x16bf16_1k(vones, (PF)[kt4], o_l, 0, 0, 0); \
  } while (0)

  float4v o_acc[4] = {};
  float4v o_l = {};

  // ---- full unmasked tiles: stage -> drain -> bar -> compute -> bar
  for (int kt = 0; kt < nfull; ++kt) {
    STAGE_KV(kt);
    asm volatile("s_waitcnt vmcnt(0)" ::: "memory");
    __builtin_amdgcn_s_barrier();

    float4v st[4];
    short4v pf[4];
    __builtin_amdgcn_s_setprio(1);
    QKH(0, st);
    __builtin_amdgcn_s_setprio(0);
    EXPH(st, pf);
    __builtin_amdgcn_s_setprio(1);
    PVH(0, pf);
    QKH(1, st);
    __builtin_amdgcn_s_setprio(0);
    EXPH(st, pf);
    __builtin_amdgcn_s_setprio(1);
    PVH(1, pf);
    __builtin_amdgcn_s_setprio(0);

    lds_barrier();   // all waves done reading before next stage overwrites
  }

  // ---- final tile kt = nfull: diagonal handling (block-uniform branches, no inner barriers)
  {
    STAGE_KV(nfull);
    asm volatile("s_waitcnt vmcnt(0)" ::: "memory");
    __builtin_amdgcn_s_barrier();

    float4v st[4];
    short4v pf[4];
    if (qt & 1) {
      QKH(0, st);
      EXPH(st, pf);      // keys all <= q rows -> unmasked
      PVH(0, pf);
      QKH(1, st);
      EXPHM(st, pf, 1);  // diagonal
      PVH(1, pf);
    } else {
      QKH(0, st);
      EXPHM(st, pf, 0);  // diagonal
      PVH(0, pf);
      // HB1 keys all > q rows -> fully masked -> skip (block-uniform)
    }
  }
#undef STAGE_KV
#undef QKH
#undef EXPH
#undef EXPHM
#undef PVH

  // all waves done reading K/V before scratch (K region) is overwritten
  lds_barrier();

  // ---- epilogue: LDS-transpose, coalesced 16B stores (l complete per-lane in o_l[0])
  float inv_l = 1.0f / o_l[0];
#pragma unroll
  for (int dt = 0; dt < 4; ++dt) {
    union { bf16 b2[2]; uint u; } p01, p23;
    p01.b2[0] = __float2bfloat16(o_acc[dt][0] * inv_l);
    p01.b2[1] = __float2bfloat16(o_acc[dt][1] * inv_l);
    p23.b2[0] = __float2bfloat16(o_acc[dt][2] * inv_l);
    p23.b2[1] = __float2bfloat16(o_acc[dt][3] * inv_l);
    *(uint*)&scratch[l16 * 72 + dt * 16 + quad * 4] = p01.u;
    *(uint*)&scratch[l16 * 72 + dt * 16 + quad * 4 + 2] = p23.u;
  }
  lgkm_wait();  // own writes visible to own reads
  uint4 r0 = *(const uint4*)&scratch[l16 * 72 + quad * 16];
  uint4 r1 = *(const uint4*)&scratch[l16 * 72 + quad * 16 + 8];
  int qrow = q0w + l16;
  bf16* vp = vals + ((size_t)(b * nS + qrow)) * nD + h * 64 + quad * 16;
  *(uint4*)(vp) = r0;
  *(uint4*)(vp + 8) = r1;
}

// ---------------------------------------------------------------- launch
extern "C" void kernel_launch(void* const* d_in, const int* in_sizes, int n_in,
                              void* d_out, int out_size, void* d_ws, size_t ws_size,
                              hipStream_t stream) {
  const float* Qin = (const float*)d_in[0];
  const float* Kin = (const float*)d_in[1];
  const float* Vin = (const float*)d_in[2];
  const float* Wq = (const float*)d_in[4];
  const float* Wk = (const float*)d_in[5];
  const float* Wv = (const float*)d_in[6];
  const float* Wo = (const float*)d_in[7];
  float* out = (float*)d_out;

  char* ws = (char*)d_ws;
  const size_t MB = 1u << 20;
  bf16* Qbf = (bf16*)(ws + 0 * MB);
  bf16* Kbf = (bf16*)(ws + 8 * MB);
  bf16* Vbf = (bf16*)(ws + 16 * MB);
  bf16* WqT = (bf16*)(ws + 24 * MB);
  bf16* WkT = (bf16*)(ws + 26 * MB);
  bf16* WvT = (bf16*)(ws + 28 * MB);
  bf16* WoT = (bf16*)(ws + 30 * MB);
  bf16* cos_t = (bf16*)(ws + 32 * MB);
  bf16* sin_t = (bf16*)(ws + 33 * MB);
  bf16* q_h = (bf16*)(ws + 34 * MB);
  bf16* k_h = (bf16*)(ws + 42 * MB);
  bf16* vt_h = (bf16*)(ws + 50 * MB);
  bf16* vals = (bf16*)(ws + 58 * MB);

  prep_kernel<<<4160, 256, 0, stream>>>(Qin, Kin, Vin, Wq, Wk, Wv, Wo,
                                        Qbf, Kbf, Vbf, WqT, WkT, WvT, WoT, cos_t, sin_t);

  gemm_qkv_kernel<<<768, 256, 0, stream>>>(Qbf, Kbf, Vbf, WqT, WkT, WvT,
                                           q_h, k_h, vt_h, cos_t, sin_t);

  attn_kernel<<<1024, 256, 0, stream>>>(q_h, k_h, vt_h, vals);

  gemm_out_kernel<<<512, 256, 0, stream>>>(vals, WoT, out);
}